// Round 7
// baseline (75.604 us; speedup 1.0000x reference)
//
#include <hip/hip_runtime.h>

// Problem: SpatialTransform
//   x: (16,256,256,32) f32 -> out: (16,256,256,32) f32
//   theta = mean_pool(x) @ W_loc + b_loc;  out = bilinear_sample(x, affine_grid(theta))
//
// R6 lesson: gather no longer load-latency-bound (MLP 8->16 bought 2us).
// R7: stage each block's affine-bbox source region in LDS (coalesced), blend
// from LDS. Fallback to direct gather if bbox exceeds LDS (block-uniform).

#define NIMG 16
#define HDIM 256
#define WDIM 256
#define CH   32
#define HW   (HDIM * WDIM)
#define BPI  64        // sum-kernel blocks per image
#define STAGE_PX 384   // LDS staging capacity in pixels (384*128B = 48KB)

typedef float f32x4 __attribute__((ext_vector_type(4)));

// ---------------------------------------------------------------------------
// Kernel 1: per-(n,c) partial sums. 1024 blocks, 4 independent acc chains.
// partials layout: [BPI][NIMG][CH]
// ---------------------------------------------------------------------------
__global__ __launch_bounds__(256) void st_sum_kernel(
    const float* __restrict__ x, float* __restrict__ partials) {
    const int n   = blockIdx.x >> 6;
    const int blk = blockIdx.x & (BPI - 1);
    const int tid = threadIdx.x;
    const int cg  = tid & 7;
    const int sp  = tid >> 3;

    const float4* xp = (const float4*)(x + (size_t)n * HW * CH);
    float4 a0 = make_float4(0.f, 0.f, 0.f, 0.f);
    float4 a1 = make_float4(0.f, 0.f, 0.f, 0.f);
    float4 a2 = make_float4(0.f, 0.f, 0.f, 0.f);
    float4 a3 = make_float4(0.f, 0.f, 0.f, 0.f);
    int s = blk * 32 + sp;   // slot stride: BPI*32 = 2048
    #pragma unroll
    for (int it = 0; it < 8; ++it) {
        float4 v0 = xp[(size_t)(s       ) * 8 + cg];
        float4 v1 = xp[(size_t)(s + 2048) * 8 + cg];
        float4 v2 = xp[(size_t)(s + 4096) * 8 + cg];
        float4 v3 = xp[(size_t)(s + 6144) * 8 + cg];
        a0.x += v0.x; a0.y += v0.y; a0.z += v0.z; a0.w += v0.w;
        a1.x += v1.x; a1.y += v1.y; a1.z += v1.z; a1.w += v1.w;
        a2.x += v2.x; a2.y += v2.y; a2.z += v2.z; a2.w += v2.w;
        a3.x += v3.x; a3.y += v3.y; a3.z += v3.z; a3.w += v3.w;
        s += 8192;
    }
    a0.x += a1.x; a0.y += a1.y; a0.z += a1.z; a0.w += a1.w;
    a2.x += a3.x; a2.y += a3.y; a2.z += a3.z; a2.w += a3.w;
    a0.x += a2.x; a0.y += a2.y; a0.z += a2.z; a0.w += a2.w;

    __shared__ float4 red[256];
    red[tid] = a0;
    __syncthreads();
    for (int stride = 16; stride >= 1; stride >>= 1) {
        if (sp < stride) {
            float4 o = red[(sp + stride) * 8 + cg];
            a0.x += o.x; a0.y += o.y; a0.z += o.z; a0.w += o.w;
            red[tid] = a0;
        }
        __syncthreads();
    }
    if (sp == 0) {
        ((float4*)(partials + ((size_t)blk * NIMG + n) * CH))[cg] = a0;
    }
}

// ---------------------------------------------------------------------------
// Kernel 2: theta recompute + LDS-staged bilinear gather.
// One block = 8x32 pixel tile. 4096 blocks; XCD swizzle: 512 blocks (=2
// images) per XCD. Thread (p,cg): column p of all 8 rows, channel group cg.
// ---------------------------------------------------------------------------
__global__ __launch_bounds__(256) void st_interp_kernel(
    const float* __restrict__ x, const float* __restrict__ partials,
    const float* __restrict__ W_loc, const float* __restrict__ b_loc,
    float* __restrict__ out) {
    const int bid = (int)blockIdx.x;
    const int swz = (bid & 7) * 512 + (bid >> 3);  // 8 XCDs contiguous
    const int n   = swz >> 8;                      // 256 blocks per image
    const int r   = swz & 255;
    const int tid = threadIdx.x;

    __shared__ float  red2[8][CH];
    __shared__ float  th_s[8];
    __shared__ float4 stage[STAGE_PX * 8];         // 48 KB

    // ---- theta from partials (identical in every block of image n) ----
    {
        const int c = tid & 31, g = tid >> 5;
        float s = 0.f;
        #pragma unroll
        for (int j = 0; j < 8; ++j)
            s += partials[(size_t)((g * 8 + j) * NIMG + n) * CH + c];
        red2[g][c] = s;
        __syncthreads();
        if (g == 0) {
            float m = 0.f;
            #pragma unroll
            for (int j = 0; j < 8; ++j) m += red2[j][c];
            red2[0][c] = m * (1.0f / (float)HW);
        }
        __syncthreads();
        if (tid < 6) {
            float acc = b_loc[tid];
            for (int c2 = 0; c2 < CH; ++c2)
                acc = fmaf(red2[0][c2], W_loc[c2 * 6 + tid], acc);
            th_s[tid] = acc;
        }
        __syncthreads();
    }
    const float t00 = th_s[0], t01 = th_s[1], t02 = th_s[2];
    const float t10 = th_s[3], t11 = th_s[4], t12 = th_s[5];

    // ---- tile geometry: 8 rows x 32 cols ----
    const int ty = r >> 3, tx = r & 7;
    const int row0 = ty * 8, col0 = tx * 32;
    const int p  = tid >> 3;       // column within tile 0..31
    const int cg = tid & 7;        // float4 channel group
    const int wo = col0 + p;

    const float gx  = fmaf((float)wo, 2.0f / 255.0f, -1.0f);
    const float ayx = fmaf(t01, gx, t02);  // uy = t00*gy + ayx
    const float axx = fmaf(t11, gx, t12);  // ux = t10*gy + axx

    // ---- source bbox of this tile (block-uniform, computed redundantly) ----
    const float gyA = fmaf((float)row0,        2.0f / 255.0f, -1.0f);
    const float gyB = fmaf((float)(row0 + 7),  2.0f / 255.0f, -1.0f);
    const float gxA = fmaf((float)col0,        2.0f / 255.0f, -1.0f);
    const float gxB = fmaf((float)(col0 + 31), 2.0f / 255.0f, -1.0f);
    const float uy1 = (fmaf(t00, gyA, fmaf(t01, gxA, t02)) + 1.0f) * 127.5f;
    const float uy2 = (fmaf(t00, gyA, fmaf(t01, gxB, t02)) + 1.0f) * 127.5f;
    const float uy3 = (fmaf(t00, gyB, fmaf(t01, gxA, t02)) + 1.0f) * 127.5f;
    const float uy4 = (fmaf(t00, gyB, fmaf(t01, gxB, t02)) + 1.0f) * 127.5f;
    const float ux1 = (fmaf(t10, gyA, fmaf(t11, gxA, t12)) + 1.0f) * 127.5f;
    const float ux2 = (fmaf(t10, gyA, fmaf(t11, gxB, t12)) + 1.0f) * 127.5f;
    const float ux3 = (fmaf(t10, gyB, fmaf(t11, gxA, t12)) + 1.0f) * 127.5f;
    const float ux4 = (fmaf(t10, gyB, fmaf(t11, gxB, t12)) + 1.0f) * 127.5f;
    const float uymin = fminf(fminf(uy1, uy2), fminf(uy3, uy4));
    const float uymax = fmaxf(fmaxf(uy1, uy2), fmaxf(uy3, uy4));
    const float uxmin = fminf(fminf(ux1, ux2), fminf(ux3, ux4));
    const float uxmax = fmaxf(fmaxf(ux1, ux2), fmaxf(ux3, ux4));
    const int iy_lo = min(max((int)floorf(uymin),     0), HDIM - 1);
    const int iy_hi = min(max((int)floorf(uymax) + 1, 0), HDIM - 1);
    const int ix_lo = min(max((int)floorf(uxmin),     0), WDIM - 1);
    const int ix_hi = min(max((int)floorf(uxmax) + 1, 0), WDIM - 1);
    const int Rr = iy_hi - iy_lo + 1;
    const int Cc = ix_hi - ix_lo + 1;
    const bool finite = (uymin == uymin) && (uymax == uymax) &&
                        (uxmin == uxmin) && (uxmax == uxmax);
    const bool fits = finite && Rr >= 1 && Cc >= 1 && (Rr * Cc) <= STAGE_PX;

    const float4* xp = (const float4*)(x + (size_t)n * HW * CH);
    f32x4* op = (f32x4*)(out + (size_t)n * HW * CH);

    if (fits) {
        // ---- stage bbox rows into LDS (coalesced contiguous reads) ----
        const int C8 = Cc * 8;
        for (int rr = 0; rr < Rr; ++rr) {
            const float4* src = xp + ((size_t)((iy_lo + rr) * WDIM + ix_lo)) * 8;
            float4* dst = stage + rr * C8;
            for (int u = tid; u < C8; u += 256) dst[u] = src[u];
        }
        __syncthreads();

        // ---- blend from LDS, one row per k ----
        #pragma unroll
        for (int k = 0; k < 8; ++k) {
            const int ho = row0 + k;
            const float gy = fmaf((float)ho, 2.0f / 255.0f, -1.0f);
            const float uy = (fmaf(t00, gy, ayx) + 1.0f) * 127.5f;
            const float ux = (fmaf(t10, gy, axx) + 1.0f) * 127.5f;
            const float fy = floorf(uy), fx = floorf(ux);
            const float ry = uy - fy, rx = ux - fx;
            const int iy0 = min(max((int)fy,     0), HDIM - 1);
            const int iy1 = min(max((int)fy + 1, 0), HDIM - 1);
            const int ix0 = min(max((int)fx,     0), WDIM - 1);
            const int ix1 = min(max((int)fx + 1, 0), WDIM - 1);
            const int ly0 = iy0 - iy_lo, ly1 = iy1 - iy_lo;
            const int lx0 = ix0 - ix_lo, lx1 = ix1 - ix_lo;
            float4 v00 = stage[(ly0 * Cc + lx0) * 8 + cg];
            float4 v01 = stage[(ly0 * Cc + lx1) * 8 + cg];
            float4 v10 = stage[(ly1 * Cc + lx0) * 8 + cg];
            float4 v11 = stage[(ly1 * Cc + lx1) * 8 + cg];
            const float w00 = (1.0f - ry) * (1.0f - rx);
            const float w01 = (1.0f - ry) * rx;
            const float w10 = ry * (1.0f - rx);
            const float w11 = ry * rx;
            f32x4 o;
            o.x = v00.x * w00 + v01.x * w01 + v10.x * w10 + v11.x * w11;
            o.y = v00.y * w00 + v01.y * w01 + v10.y * w10 + v11.y * w11;
            o.z = v00.z * w00 + v01.z * w01 + v10.z * w10 + v11.z * w11;
            o.w = v00.w * w00 + v01.w * w01 + v10.w * w10 + v11.w * w11;
            __builtin_nontemporal_store(o, &op[(size_t)(ho * WDIM + wo) * 8 + cg]);
        }
    } else {
        // ---- fallback: direct gather (correct for arbitrary theta) ----
        for (int k = 0; k < 8; ++k) {
            const int ho = row0 + k;
            const float gy = fmaf((float)ho, 2.0f / 255.0f, -1.0f);
            const float uy = (fmaf(t00, gy, ayx) + 1.0f) * 127.5f;
            const float ux = (fmaf(t10, gy, axx) + 1.0f) * 127.5f;
            const float fy = floorf(uy), fx = floorf(ux);
            const float ry = uy - fy, rx = ux - fx;
            const int iy0 = min(max((int)fy,     0), HDIM - 1);
            const int iy1 = min(max((int)fy + 1, 0), HDIM - 1);
            const int ix0 = min(max((int)fx,     0), WDIM - 1);
            const int ix1 = min(max((int)fx + 1, 0), WDIM - 1);
            float4 v00 = xp[(size_t)(iy0 * WDIM + ix0) * 8 + cg];
            float4 v01 = xp[(size_t)(iy0 * WDIM + ix1) * 8 + cg];
            float4 v10 = xp[(size_t)(iy1 * WDIM + ix0) * 8 + cg];
            float4 v11 = xp[(size_t)(iy1 * WDIM + ix1) * 8 + cg];
            const float w00 = (1.0f - ry) * (1.0f - rx);
            const float w01 = (1.0f - ry) * rx;
            const float w10 = ry * (1.0f - rx);
            const float w11 = ry * rx;
            f32x4 o;
            o.x = v00.x * w00 + v01.x * w01 + v10.x * w10 + v11.x * w11;
            o.y = v00.y * w00 + v01.y * w01 + v10.y * w10 + v11.y * w11;
            o.z = v00.z * w00 + v01.z * w01 + v10.z * w10 + v11.z * w11;
            o.w = v00.w * w00 + v01.w * w01 + v10.w * w10 + v11.w * w11;
            __builtin_nontemporal_store(o, &op[(size_t)(ho * WDIM + wo) * 8 + cg]);
        }
    }
}

extern "C" void kernel_launch(void* const* d_in, const int* in_sizes, int n_in,
                              void* d_out, int out_size, void* d_ws, size_t ws_size,
                              hipStream_t stream) {
    const float* x     = (const float*)d_in[0];
    const float* W_loc = (const float*)d_in[1];
    const float* b_loc = (const float*)d_in[2];
    float* out = (float*)d_out;

    float* partials = (float*)d_ws;  // [BPI][NIMG][CH]

    st_sum_kernel<<<NIMG * BPI, 256, 0, stream>>>(x, partials);
    st_interp_kernel<<<NIMG * (HW / 256), 256, 0, stream>>>(
        x, partials, W_loc, b_loc, out);
}